// Round 1
// baseline (2280.760 us; speedup 1.0000x reference)
//
#include <hip/hip_runtime.h>
#include <hip/hip_bf16.h>

#define HIDF 96
#define INF 256

// ---------- transpose W_lin [96,256] -> Wt [256,96] ----------
__global__ void transpose_wlin(const float* __restrict__ W, float* __restrict__ Wt) {
    int t = blockIdx.x * blockDim.x + threadIdx.x;
    if (t >= HIDF * INF) return;
    int k = t / HIDF, f = t % HIDF;
    Wt[t] = W[f * INF + k];
}

// ---------- kernel A: h @ W_lin.T + b ; emit g1 = lin*norm1, g2 = lin*norm2, ai ----------
__global__ __launch_bounds__(256) void lin_kernel(
    const float* __restrict__ h, const float* __restrict__ Wt,
    const float* __restrict__ b_lin, const float* __restrict__ W_al,
    const float* __restrict__ b_al,
    const float* __restrict__ norm1, const float* __restrict__ norm2,
    float* __restrict__ g1, float* __restrict__ g2, float* __restrict__ ai, int N)
{
    int n = blockIdx.x * blockDim.x + threadIdx.x;
    if (n >= N) return;
    float acc[HIDF];
    #pragma unroll
    for (int f = 0; f < HIDF; ++f) acc[f] = b_lin[f];

    const float4* hrow = reinterpret_cast<const float4*>(h + (size_t)n * INF);
    for (int k4 = 0; k4 < INF / 4; ++k4) {
        float4 hv = hrow[k4];
        const float* w0 = Wt + (k4 * 4 + 0) * HIDF;   // wave-uniform -> s_load
        const float* w1 = Wt + (k4 * 4 + 1) * HIDF;
        const float* w2 = Wt + (k4 * 4 + 2) * HIDF;
        const float* w3 = Wt + (k4 * 4 + 3) * HIDF;
        #pragma unroll
        for (int f = 0; f < HIDF; ++f) {
            acc[f] = fmaf(hv.x, w0[f], acc[f]);
            acc[f] = fmaf(hv.y, w1[f], acc[f]);
            acc[f] = fmaf(hv.z, w2[f], acc[f]);
            acc[f] = fmaf(hv.w, w3[f], acc[f]);
        }
    }

    float aiv = b_al[0];
    #pragma unroll
    for (int f = 0; f < HIDF; ++f) aiv = fmaf(W_al[f], acc[f], aiv);

    float n1 = norm1[n], n2 = norm2[n];
    float4* g1r = reinterpret_cast<float4*>(g1 + (size_t)n * HIDF);
    float4* g2r = reinterpret_cast<float4*>(g2 + (size_t)n * HIDF);
    #pragma unroll
    for (int c = 0; c < HIDF / 4; ++c) {
        float4 v1, v2;
        v1.x = acc[4*c+0] * n1; v1.y = acc[4*c+1] * n1;
        v1.z = acc[4*c+2] * n1; v1.w = acc[4*c+3] * n1;
        v2.x = acc[4*c+0] * n2; v2.y = acc[4*c+1] * n2;
        v2.z = acc[4*c+2] * n2; v2.w = acc[4*c+3] * n2;
        g1r[c] = v1; g2r[c] = v2;
    }
    ai[n] = aiv;
}

// ---------- kernel B: both graphs' scatter-sum via float atomics ----------
// thread t handles (edge, 4-float chunk); first perG threads = graph1, next perG = graph2
__global__ __launch_bounds__(256) void agg_kernel(
    const float* __restrict__ g1, const int* __restrict__ src1, const int* __restrict__ dst1,
    float* __restrict__ acc1,
    const float* __restrict__ g2, const int* __restrict__ src2, const int* __restrict__ dst2,
    float* __restrict__ acc2, int perG)
{
    int t = blockIdx.x * blockDim.x + threadIdx.x;
    const float* g; const int* sp; const int* dp; float* ap;
    if (t < perG) { g = g1; sp = src1; dp = dst1; ap = acc1; }
    else {
        t -= perG;
        if (t >= perG) return;
        g = g2; sp = src2; dp = dst2; ap = acc2;
    }
    int e = t / 24, c = t % 24;
    int s = sp[e], d = dp[e];
    float4 v = *reinterpret_cast<const float4*>(g + (size_t)s * HIDF + c * 4);
    float* outp = ap + (size_t)d * HIDF + c * 4;
    atomicAdd(outp + 0, v.x);
    atomicAdd(outp + 1, v.y);
    atomicAdd(outp + 2, v.z);
    atomicAdd(outp + 3, v.w);
}

// ---------- kernel C: attention combine + final FC ----------
__global__ __launch_bounds__(256) void comb_kernel(
    const float* __restrict__ acc1, const float* __restrict__ acc2,
    const float* __restrict__ norm1, const float* __restrict__ norm2,
    const float* __restrict__ ai,
    const float* __restrict__ W_ar, const float* __restrict__ b_ar,
    const float* __restrict__ W_fc, const float* __restrict__ b_fc,
    float* __restrict__ out, int N)
{
    int n = blockIdx.x * blockDim.x + threadIdx.x;
    if (n >= N) return;
    const float4* r1 = reinterpret_cast<const float4*>(acc1 + (size_t)n * HIDF);
    const float4* r2 = reinterpret_cast<const float4*>(acc2 + (size_t)n * HIDF);

    // pass 1: d1 = dot(W_ar, acc1_row), d2 = dot(W_ar, acc2_row)
    float d1 = 0.f, d2 = 0.f;
    #pragma unroll
    for (int c = 0; c < HIDF / 4; ++c) {
        float4 v1 = r1[c], v2 = r2[c];
        const float* w = W_ar + c * 4;            // wave-uniform -> s_load
        d1 = fmaf(v1.x, w[0], d1); d1 = fmaf(v1.y, w[1], d1);
        d1 = fmaf(v1.z, w[2], d1); d1 = fmaf(v1.w, w[3], d1);
        d2 = fmaf(v2.x, w[0], d2); d2 = fmaf(v2.y, w[1], d2);
        d2 = fmaf(v2.z, w[2], d2); d2 = fmaf(v2.w, w[3], d2);
    }

    float n1 = norm1[n], n2 = norm2[n], aiv = ai[n], br = b_ar[0];
    // h1 = norm1*acc1  =>  aj1 = norm1*d1 + b_ar
    float x1 = aiv + n1 * d1 + br;
    float x2 = aiv + n2 * d2 + br;
    float l1 = x1 >= 0.f ? x1 : 0.2f * x1;
    float l2 = x2 >= 0.f ? x2 : 0.2f * x2;
    float e1 = fminf(fmaxf(__expf(l1), -10.f), 10.f);
    float e2 = fminf(fmaxf(__expf(l2), -10.f), 10.f);
    float inv = 1.f / (e1 + e2);
    float s1 = e1 * inv * n1;   // weight folded with dst-norm: w1*h1 = (w1*n1)*acc1
    float s2 = e2 * inv * n2;

    // pass 2: comb row (rows are hot in L1/L2 from pass 1)
    float comb[HIDF];
    #pragma unroll
    for (int c = 0; c < HIDF / 4; ++c) {
        float4 v1 = r1[c], v2 = r2[c];
        comb[4*c+0] = s1 * v1.x + s2 * v2.x;
        comb[4*c+1] = s1 * v1.y + s2 * v2.y;
        comb[4*c+2] = s1 * v1.z + s2 * v2.z;
        comb[4*c+3] = s1 * v1.w + s2 * v2.w;
    }

    // out = comb @ W_fc.T + b_fc ; 4 output features at a time
    float4* orow = reinterpret_cast<float4*>(out + (size_t)n * HIDF);
    for (int o4 = 0; o4 < HIDF / 4; ++o4) {
        float a0 = b_fc[o4*4+0], a1 = b_fc[o4*4+1];
        float a2 = b_fc[o4*4+2], a3 = b_fc[o4*4+3];
        const float* wr0 = W_fc + (size_t)(o4*4+0) * HIDF;  // uniform -> s_load
        const float* wr1 = W_fc + (size_t)(o4*4+1) * HIDF;
        const float* wr2 = W_fc + (size_t)(o4*4+2) * HIDF;
        const float* wr3 = W_fc + (size_t)(o4*4+3) * HIDF;
        #pragma unroll
        for (int k = 0; k < HIDF; ++k) {
            a0 = fmaf(comb[k], wr0[k], a0);
            a1 = fmaf(comb[k], wr1[k], a1);
            a2 = fmaf(comb[k], wr2[k], a2);
            a3 = fmaf(comb[k], wr3[k], a3);
        }
        float4 ov; ov.x = a0; ov.y = a1; ov.z = a2; ov.w = a3;
        orow[o4] = ov;
    }
}

extern "C" void kernel_launch(void* const* d_in, const int* in_sizes, int n_in,
                              void* d_out, int out_size, void* d_ws, size_t ws_size,
                              hipStream_t stream) {
    const float* h     = (const float*)d_in[0];
    const float* norm1 = (const float*)d_in[1];
    const float* norm2 = (const float*)d_in[2];
    const int*   src1  = (const int*)d_in[3];
    const int*   dst1  = (const int*)d_in[4];
    const int*   src2  = (const int*)d_in[5];
    const int*   dst2  = (const int*)d_in[6];
    const float* W_lin = (const float*)d_in[7];
    const float* b_lin = (const float*)d_in[8];
    const float* W_fc  = (const float*)d_in[9];
    const float* b_fc  = (const float*)d_in[10];
    const float* W_al  = (const float*)d_in[11];
    const float* b_al  = (const float*)d_in[12];
    const float* W_ar  = (const float*)d_in[13];
    const float* b_ar  = (const float*)d_in[14];

    const int N = in_sizes[1];          // norm1 is [N,1]
    const int E = in_sizes[3];          // src1 is [E]

    // workspace layout (floats)
    float* ws   = (float*)d_ws;
    float* Wt   = ws;                                   // 256*96
    float* ai   = ws + INF * HIDF;                      // N
    size_t off  = (size_t)INF * HIDF + (size_t)((N + 3) & ~3);
    float* g1   = ws + off;                             // N*96
    float* g2   = g1 + (size_t)N * HIDF;
    float* acc1 = g2 + (size_t)N * HIDF;
    float* acc2 = acc1 + (size_t)N * HIDF;

    // zero the accumulators (graph-capture-safe)
    hipMemsetAsync(acc1, 0, 2ull * (size_t)N * HIDF * sizeof(float), stream);

    transpose_wlin<<<(HIDF * INF + 255) / 256, 256, 0, stream>>>(W_lin, Wt);

    lin_kernel<<<(N + 255) / 256, 256, 0, stream>>>(
        h, Wt, b_lin, W_al, b_al, norm1, norm2, g1, g2, ai, N);

    int perG = E * 24;                  // (edge, float4-chunk) work items per graph
    int total = 2 * perG;
    agg_kernel<<<(total + 255) / 256, 256, 0, stream>>>(
        g1, src1, dst1, acc1, g2, src2, dst2, acc2, perG);

    comb_kernel<<<(N + 255) / 256, 256, 0, stream>>>(
        acc1, acc2, norm1, norm2, ai, W_ar, b_ar, W_fc, b_fc, (float*)d_out, N);
}

// Round 2
// 611.912 us; speedup vs baseline: 3.7273x; 3.7273x over previous
//
#include <hip/hip_runtime.h>
#include <hip/hip_bf16.h>

#define HIDF 96
#define INF 256

// ---------- transpose W_lin [96,256] -> Wt [256,96] ----------
__global__ void transpose_wlin(const float* __restrict__ W, float* __restrict__ Wt) {
    int t = blockIdx.x * blockDim.x + threadIdx.x;
    if (t >= HIDF * INF) return;
    int k = t / HIDF, f = t % HIDF;
    Wt[t] = W[f * INF + k];
}

// ---------- CSR build: histogram over concatenated [dst1 ; N+dst2] ----------
__global__ __launch_bounds__(256) void hist_kernel(
    const int* __restrict__ dst1, const int* __restrict__ dst2,
    int* __restrict__ cnt, int E, int N)
{
    int t = blockIdx.x * blockDim.x + threadIdx.x;
    if (t >= 2 * E) return;
    if (t < E) atomicAdd(&cnt[dst1[t]], 1);
    else       atomicAdd(&cnt[N + dst2[t - E]], 1);
}

// ---------- scan stage 1: per-block exclusive scan of cnt[2N], block sums ----------
__global__ __launch_bounds__(256) void scan_part(
    const int* __restrict__ cnt, int* __restrict__ offs, int* __restrict__ bsum, int n)
{
    __shared__ int s[256];
    int i = blockIdx.x * 256 + threadIdx.x;
    int v = (i < n) ? cnt[i] : 0;
    s[threadIdx.x] = v;
    __syncthreads();
    for (int d = 1; d < 256; d <<= 1) {
        int t = (threadIdx.x >= d) ? s[threadIdx.x - d] : 0;
        __syncthreads();
        s[threadIdx.x] += t;
        __syncthreads();
    }
    int inc = s[threadIdx.x];
    if (i < n) offs[i] = inc - v;          // exclusive
    if (threadIdx.x == 255) bsum[blockIdx.x] = inc;
}

// ---------- scan stage 2: exclusive scan of block sums (single block, nb<=512) ----------
__global__ __launch_bounds__(512) void scan_top(int* __restrict__ bsum, int nb)
{
    __shared__ int s[512];
    int i = threadIdx.x;
    int v = (i < nb) ? bsum[i] : 0;
    s[i] = v;
    __syncthreads();
    for (int d = 1; d < 512; d <<= 1) {
        int t = (i >= d) ? s[i - d] : 0;
        __syncthreads();
        s[i] += t;
        __syncthreads();
    }
    if (i < nb) bsum[i] = s[i] - v;        // exclusive
}

// ---------- scan stage 3: add block offsets; init cursor ----------
__global__ __launch_bounds__(256) void scan_add(
    int* __restrict__ offs, int* __restrict__ cursor,
    const int* __restrict__ bsum, int n)
{
    int i = blockIdx.x * 256 + threadIdx.x;
    if (i >= n) return;
    int o = offs[i] + bsum[blockIdx.x];
    offs[i] = o;
    cursor[i] = o;
}

// ---------- scatter edge ids into CSR slots ----------
__global__ __launch_bounds__(256) void scatter_kernel(
    const int* __restrict__ dst1, const int* __restrict__ dst2,
    int* __restrict__ cursor, int* __restrict__ eid, int E, int N)
{
    int t = blockIdx.x * blockDim.x + threadIdx.x;
    if (t >= 2 * E) return;
    if (t < E) {
        int p = atomicAdd(&cursor[dst1[t]], 1);
        eid[p] = t;
    } else {
        int e = t - E;
        int p = atomicAdd(&cursor[N + dst2[e]], 1);
        eid[p] = e;
    }
}

// ---------- kernel A: lin = h @ W_lin.T + b ; ai = dot(W_al, lin) + b_al ----------
__global__ __launch_bounds__(256) void lin_kernel(
    const float* __restrict__ h, const float* __restrict__ Wt,
    const float* __restrict__ b_lin, const float* __restrict__ W_al,
    const float* __restrict__ b_al,
    float* __restrict__ lin, float* __restrict__ ai, int N)
{
    int n = blockIdx.x * blockDim.x + threadIdx.x;
    if (n >= N) return;
    float acc[HIDF];
    #pragma unroll
    for (int f = 0; f < HIDF; ++f) acc[f] = b_lin[f];

    const float4* hrow = reinterpret_cast<const float4*>(h + (size_t)n * INF);
    for (int k4 = 0; k4 < INF / 4; ++k4) {
        float4 hv = hrow[k4];
        const float* w0 = Wt + (k4 * 4 + 0) * HIDF;   // wave-uniform
        const float* w1 = Wt + (k4 * 4 + 1) * HIDF;
        const float* w2 = Wt + (k4 * 4 + 2) * HIDF;
        const float* w3 = Wt + (k4 * 4 + 3) * HIDF;
        #pragma unroll
        for (int f = 0; f < HIDF; ++f) {
            acc[f] = fmaf(hv.x, w0[f], acc[f]);
            acc[f] = fmaf(hv.y, w1[f], acc[f]);
            acc[f] = fmaf(hv.z, w2[f], acc[f]);
            acc[f] = fmaf(hv.w, w3[f], acc[f]);
        }
    }

    float aiv = b_al[0];
    #pragma unroll
    for (int f = 0; f < HIDF; ++f) aiv = fmaf(W_al[f], acc[f], aiv);

    float4* lr = reinterpret_cast<float4*>(lin + (size_t)n * HIDF);
    #pragma unroll
    for (int c = 0; c < HIDF / 4; ++c) {
        float4 v;
        v.x = acc[4*c+0]; v.y = acc[4*c+1]; v.z = acc[4*c+2]; v.w = acc[4*c+3];
        lr[c] = v;
    }
    ai[n] = aiv;
}

// ---------- kernel B: CSR aggregation, no atomics ----------
// thread t -> (idx, c): idx in [0,2N) node-graph slot, c in [0,24) float4 chunk
__global__ __launch_bounds__(256) void agg_csr(
    const float* __restrict__ lin,
    const float* __restrict__ norm1, const float* __restrict__ norm2,
    const int* __restrict__ src1, const int* __restrict__ src2,
    const int* __restrict__ offs, const int* __restrict__ cnt,
    const int* __restrict__ eid,
    float* __restrict__ acc1, float* __restrict__ acc2, int N)
{
    int t = blockIdx.x * blockDim.x + threadIdx.x;
    int idx = t / 24, c = t % 24;
    if (idx >= 2 * N) return;
    bool is2 = idx >= N;
    int node = is2 ? idx - N : idx;
    const int*   src = is2 ? src2 : src1;
    const float* nrm = is2 ? norm2 : norm1;

    int start = offs[idx];
    int deg   = cnt[idx];
    float4 a; a.x = 0.f; a.y = 0.f; a.z = 0.f; a.w = 0.f;
    for (int k = 0; k < deg; ++k) {
        int e = eid[start + k];      // broadcast within 24-group
        int s = src[e];              // broadcast
        float nv = nrm[s];           // broadcast
        float4 v = *reinterpret_cast<const float4*>(lin + (size_t)s * HIDF + c * 4);
        a.x = fmaf(v.x, nv, a.x);
        a.y = fmaf(v.y, nv, a.y);
        a.z = fmaf(v.z, nv, a.z);
        a.w = fmaf(v.w, nv, a.w);
    }
    float* ap = (is2 ? acc2 : acc1) + (size_t)node * HIDF + c * 4;
    *reinterpret_cast<float4*>(ap) = a;
}

// ---------- kernel C: attention combine + final FC ----------
__global__ __launch_bounds__(256) void comb_kernel(
    const float* __restrict__ acc1, const float* __restrict__ acc2,
    const float* __restrict__ norm1, const float* __restrict__ norm2,
    const float* __restrict__ ai,
    const float* __restrict__ W_ar, const float* __restrict__ b_ar,
    const float* __restrict__ W_fc, const float* __restrict__ b_fc,
    float* __restrict__ out, int N)
{
    int n = blockIdx.x * blockDim.x + threadIdx.x;
    if (n >= N) return;
    const float4* r1 = reinterpret_cast<const float4*>(acc1 + (size_t)n * HIDF);
    const float4* r2 = reinterpret_cast<const float4*>(acc2 + (size_t)n * HIDF);

    float d1 = 0.f, d2 = 0.f;
    #pragma unroll
    for (int c = 0; c < HIDF / 4; ++c) {
        float4 v1 = r1[c], v2 = r2[c];
        const float* w = W_ar + c * 4;
        d1 = fmaf(v1.x, w[0], d1); d1 = fmaf(v1.y, w[1], d1);
        d1 = fmaf(v1.z, w[2], d1); d1 = fmaf(v1.w, w[3], d1);
        d2 = fmaf(v2.x, w[0], d2); d2 = fmaf(v2.y, w[1], d2);
        d2 = fmaf(v2.z, w[2], d2); d2 = fmaf(v2.w, w[3], d2);
    }

    float n1 = norm1[n], n2 = norm2[n], aiv = ai[n], br = b_ar[0];
    float x1 = aiv + n1 * d1 + br;
    float x2 = aiv + n2 * d2 + br;
    float l1 = x1 >= 0.f ? x1 : 0.2f * x1;
    float l2 = x2 >= 0.f ? x2 : 0.2f * x2;
    float e1 = fminf(fmaxf(__expf(l1), -10.f), 10.f);
    float e2 = fminf(fmaxf(__expf(l2), -10.f), 10.f);
    float inv = 1.f / (e1 + e2);
    float s1 = e1 * inv * n1;
    float s2 = e2 * inv * n2;

    float comb[HIDF];
    #pragma unroll
    for (int c = 0; c < HIDF / 4; ++c) {
        float4 v1 = r1[c], v2 = r2[c];
        comb[4*c+0] = s1 * v1.x + s2 * v2.x;
        comb[4*c+1] = s1 * v1.y + s2 * v2.y;
        comb[4*c+2] = s1 * v1.z + s2 * v2.z;
        comb[4*c+3] = s1 * v1.w + s2 * v2.w;
    }

    float4* orow = reinterpret_cast<float4*>(out + (size_t)n * HIDF);
    for (int o4 = 0; o4 < HIDF / 4; ++o4) {
        float a0 = b_fc[o4*4+0], a1 = b_fc[o4*4+1];
        float a2 = b_fc[o4*4+2], a3 = b_fc[o4*4+3];
        const float* wr0 = W_fc + (size_t)(o4*4+0) * HIDF;
        const float* wr1 = W_fc + (size_t)(o4*4+1) * HIDF;
        const float* wr2 = W_fc + (size_t)(o4*4+2) * HIDF;
        const float* wr3 = W_fc + (size_t)(o4*4+3) * HIDF;
        #pragma unroll
        for (int k = 0; k < HIDF; ++k) {
            a0 = fmaf(comb[k], wr0[k], a0);
            a1 = fmaf(comb[k], wr1[k], a1);
            a2 = fmaf(comb[k], wr2[k], a2);
            a3 = fmaf(comb[k], wr3[k], a3);
        }
        float4 ov; ov.x = a0; ov.y = a1; ov.z = a2; ov.w = a3;
        orow[o4] = ov;
    }
}

extern "C" void kernel_launch(void* const* d_in, const int* in_sizes, int n_in,
                              void* d_out, int out_size, void* d_ws, size_t ws_size,
                              hipStream_t stream) {
    const float* h     = (const float*)d_in[0];
    const float* norm1 = (const float*)d_in[1];
    const float* norm2 = (const float*)d_in[2];
    const int*   src1  = (const int*)d_in[3];
    const int*   dst1  = (const int*)d_in[4];
    const int*   src2  = (const int*)d_in[5];
    const int*   dst2  = (const int*)d_in[6];
    const float* W_lin = (const float*)d_in[7];
    const float* b_lin = (const float*)d_in[8];
    const float* W_fc  = (const float*)d_in[9];
    const float* b_fc  = (const float*)d_in[10];
    const float* W_al  = (const float*)d_in[11];
    const float* b_al  = (const float*)d_in[12];
    const float* W_ar  = (const float*)d_in[13];
    const float* b_ar  = (const float*)d_in[14];

    const int N = in_sizes[1];          // norm1 is [N,1]
    const int E = in_sizes[3];          // src1 is [E]

    // ---- workspace layout ----
    char* p = (char*)d_ws;
    auto alloc = [&](size_t bytes) {
        char* r = p;
        p += (bytes + 255) & ~(size_t)255;
        return r;
    };
    float* Wt     = (float*)alloc((size_t)INF * HIDF * 4);
    float* ai     = (float*)alloc((size_t)N * 4);
    float* lin    = (float*)alloc((size_t)N * HIDF * 4);
    float* acc1   = (float*)alloc((size_t)N * HIDF * 4);
    float* acc2   = (float*)alloc((size_t)N * HIDF * 4);
    int*   cnt    = (int*)alloc((size_t)2 * N * 4);
    int*   offs   = (int*)alloc((size_t)2 * N * 4);
    int*   cursor = (int*)alloc((size_t)2 * N * 4);
    int*   eid    = (int*)alloc((size_t)2 * E * 4);
    int*   bsum   = (int*)alloc(1024 * 4);

    const int n2N = 2 * N;
    const int nb  = (n2N + 255) / 256;   // 391 for N=50000 (<=512 required)

    // zero histogram
    hipMemsetAsync(cnt, 0, (size_t)n2N * 4, stream);

    transpose_wlin<<<(HIDF * INF + 255) / 256, 256, 0, stream>>>(W_lin, Wt);

    // CSR build
    hist_kernel<<<(2 * E + 255) / 256, 256, 0, stream>>>(dst1, dst2, cnt, E, N);
    scan_part<<<nb, 256, 0, stream>>>(cnt, offs, bsum, n2N);
    scan_top<<<1, 512, 0, stream>>>(bsum, nb);
    scan_add<<<nb, 256, 0, stream>>>(offs, cursor, bsum, n2N);
    scatter_kernel<<<(2 * E + 255) / 256, 256, 0, stream>>>(dst1, dst2, cursor, eid, E, N);

    // dense phases
    lin_kernel<<<(N + 255) / 256, 256, 0, stream>>>(h, Wt, b_lin, W_al, b_al, lin, ai, N);

    int aggThreads = n2N * 24;
    agg_csr<<<(aggThreads + 255) / 256, 256, 0, stream>>>(
        lin, norm1, norm2, src1, src2, offs, cnt, eid, acc1, acc2, N);

    comb_kernel<<<(N + 255) / 256, 256, 0, stream>>>(
        acc1, acc2, norm1, norm2, ai, W_ar, b_ar, W_fc, b_fc, (float*)d_out, N);
}

// Round 3
// 325.114 us; speedup vs baseline: 7.0153x; 1.8821x over previous
//
#include <hip/hip_runtime.h>
#include <hip/hip_bf16.h>

#define HIDF 96
#define INF 256

typedef short bf16x8 __attribute__((ext_vector_type(8)));
typedef float f32x4 __attribute__((ext_vector_type(4)));

static __device__ inline short f2bf(float f) {
    __hip_bfloat16 b = __float2bfloat16(f);
    short s;
    __builtin_memcpy(&s, &b, 2);
    return s;
}
static __device__ inline float bf2f(unsigned u) {
    union { unsigned x; float f; } v;
    v.x = u << 16;
    return v.f;
}

// ---------- pack W_lin and W_fc into MFMA B-fragment layout ----------
// Bp[ (kt*6+nt)*64 + lane ][j] = bf16( W[n][k] ), n = nt*16+(lane&15), k = kt*32+(lane>>4)*8+j
__global__ __launch_bounds__(256) void pack_weights(
    const float* __restrict__ W_lin, const float* __restrict__ W_fc,
    short* __restrict__ Bp1, short* __restrict__ Bp2)
{
    int t = blockIdx.x * 256 + threadIdx.x;
    if (t < 8 * 6 * 64) {
        int kt = t / (6 * 64), rem = t % (6 * 64), nt = rem / 64, l = rem % 64;
        int n = nt * 16 + (l & 15);
        int k0 = kt * 32 + ((l >> 4) << 3);
        short v[8];
        #pragma unroll
        for (int j = 0; j < 8; ++j) v[j] = f2bf(W_lin[n * INF + k0 + j]);
        #pragma unroll
        for (int j = 0; j < 8; ++j) Bp1[(size_t)t * 8 + j] = v[j];
    } else if (t < 8 * 6 * 64 + 3 * 6 * 64) {
        int u = t - 8 * 6 * 64;
        int kt = u / (6 * 64), rem = u % (6 * 64), nt = rem / 64, l = rem % 64;
        int n = nt * 16 + (l & 15);
        int k0 = kt * 32 + ((l >> 4) << 3);
        short v[8];
        #pragma unroll
        for (int j = 0; j < 8; ++j) v[j] = f2bf(W_fc[n * HIDF + k0 + j]);
        #pragma unroll
        for (int j = 0; j < 8; ++j) Bp2[(size_t)u * 8 + j] = v[j];
    }
}

// ---------- CSR build ----------
__global__ __launch_bounds__(256) void hist_kernel(
    const int* __restrict__ dst1, const int* __restrict__ dst2,
    int* __restrict__ cnt, int E, int N)
{
    int t = blockIdx.x * blockDim.x + threadIdx.x;
    if (t >= 2 * E) return;
    if (t < E) atomicAdd(&cnt[dst1[t]], 1);
    else       atomicAdd(&cnt[N + dst2[t - E]], 1);
}

__global__ __launch_bounds__(256) void scan_part(
    const int* __restrict__ cnt, int* __restrict__ offs, int* __restrict__ bsum, int n)
{
    __shared__ int s[256];
    int i = blockIdx.x * 256 + threadIdx.x;
    int v = (i < n) ? cnt[i] : 0;
    s[threadIdx.x] = v;
    __syncthreads();
    for (int d = 1; d < 256; d <<= 1) {
        int t = (threadIdx.x >= d) ? s[threadIdx.x - d] : 0;
        __syncthreads();
        s[threadIdx.x] += t;
        __syncthreads();
    }
    int inc = s[threadIdx.x];
    if (i < n) offs[i] = inc - v;
    if (threadIdx.x == 255) bsum[blockIdx.x] = inc;
}

__global__ __launch_bounds__(512) void scan_top(int* __restrict__ bsum, int nb)
{
    __shared__ int s[512];
    int i = threadIdx.x;
    int v = (i < nb) ? bsum[i] : 0;
    s[i] = v;
    __syncthreads();
    for (int d = 1; d < 512; d <<= 1) {
        int t = (i >= d) ? s[i - d] : 0;
        __syncthreads();
        s[i] += t;
        __syncthreads();
    }
    if (i < nb) bsum[i] = s[i] - v;
}

__global__ __launch_bounds__(256) void scan_add(
    int* __restrict__ offs, int* __restrict__ cursor,
    const int* __restrict__ bsum, int n)
{
    int i = blockIdx.x * 256 + threadIdx.x;
    if (i >= n) return;
    int o = offs[i] + bsum[blockIdx.x];
    offs[i] = o;
    cursor[i] = o;
}

__global__ __launch_bounds__(256) void scatter_kernel(
    const int* __restrict__ dst1, const int* __restrict__ dst2,
    int* __restrict__ cursor, int* __restrict__ eid, int E, int N)
{
    int t = blockIdx.x * blockDim.x + threadIdx.x;
    if (t >= 2 * E) return;
    if (t < E) {
        int p = atomicAdd(&cursor[dst1[t]], 1);
        eid[p] = t;
    } else {
        int e = t - E;
        int p = atomicAdd(&cursor[N + dst2[e]], 1);
        eid[p] = e;
    }
}

// ---------- GEMM1: lin_bf16 = bf16(h) @ W_lin.T + b_lin ; ai = W_al . lin + b_al ----------
// block = 4 waves, each wave does 16 rows x 96 cols; K = 256 (8 ktiles)
__global__ __launch_bounds__(256) void gemm_lin(
    const float* __restrict__ h, const short* __restrict__ Bp1,
    const float* __restrict__ b_lin, const float* __restrict__ W_al,
    const float* __restrict__ b_al,
    unsigned short* __restrict__ linb, float* __restrict__ ai, int N)
{
    __shared__ short Bs[8 * 6 * 64 * 8];   // 48 KiB
    // stage Bpack into LDS
    {
        const uint4* gsrc = reinterpret_cast<const uint4*>(Bp1);
        uint4* ldst = reinterpret_cast<uint4*>(Bs);
        for (int i = threadIdx.x; i < 8 * 6 * 64 * 8 / 8; i += 256) ldst[i] = gsrc[i];
    }
    __syncthreads();

    int lane = threadIdx.x & 63;
    int wid = threadIdx.x >> 6;
    int m0 = blockIdx.x * 64 + wid * 16;
    int arow = m0 + (lane & 15);
    int rc = arow < N ? arow : N - 1;
    const float* hrow = h + (size_t)rc * INF;
    int koff = (lane >> 4) << 3;

    f32x4 acc[6];
    #pragma unroll
    for (int nt = 0; nt < 6; ++nt) acc[nt] = (f32x4){0.f, 0.f, 0.f, 0.f};

    for (int kt = 0; kt < 8; ++kt) {
        const float4* hp = reinterpret_cast<const float4*>(hrow + kt * 32 + koff);
        float4 f0 = hp[0], f1 = hp[1];
        bf16x8 a8;
        a8[0] = f2bf(f0.x); a8[1] = f2bf(f0.y); a8[2] = f2bf(f0.z); a8[3] = f2bf(f0.w);
        a8[4] = f2bf(f1.x); a8[5] = f2bf(f1.y); a8[6] = f2bf(f1.z); a8[7] = f2bf(f1.w);
        #pragma unroll
        for (int nt = 0; nt < 6; ++nt) {
            bf16x8 b8 = *reinterpret_cast<const bf16x8*>(&Bs[((kt * 6 + nt) * 64 + lane) * 8]);
            acc[nt] = __builtin_amdgcn_mfma_f32_16x16x32_bf16(a8, b8, acc[nt], 0, 0, 0);
        }
    }

    // epilogue: add bias, emit bf16 lin, accumulate ai partials
    float pai[4] = {0.f, 0.f, 0.f, 0.f};
    int rbase = m0 + ((lane >> 4) << 2);
    #pragma unroll
    for (int nt = 0; nt < 6; ++nt) {
        int col = nt * 16 + (lane & 15);
        float bl = b_lin[col];
        float wal = W_al[col];
        #pragma unroll
        for (int r = 0; r < 4; ++r) {
            float v = acc[nt][r] + bl;
            int rrow = rbase + r;
            if (rrow < N) linb[(size_t)rrow * HIDF + col] = (unsigned short)f2bf(v);
            pai[r] = fmaf(wal, v, pai[r]);
        }
    }
    #pragma unroll
    for (int r = 0; r < 4; ++r) {
        float p = pai[r];
        p += __shfl_xor(p, 1);
        p += __shfl_xor(p, 2);
        p += __shfl_xor(p, 4);
        p += __shfl_xor(p, 8);
        int rrow = rbase + r;
        if ((lane & 15) == 0 && rrow < N) ai[rrow] = p + b_al[0];
    }
}

// ---------- agg: CSR aggregation over bf16 lin table ----------
// thread -> (idx, c): idx in [0,2N), c in [0,12) chunks of 8 bf16
__global__ __launch_bounds__(256) void agg_csr(
    const unsigned short* __restrict__ linb,
    const float* __restrict__ norm1, const float* __restrict__ norm2,
    const int* __restrict__ src1, const int* __restrict__ src2,
    const int* __restrict__ offs, const int* __restrict__ cnt,
    const int* __restrict__ eid,
    float* __restrict__ acc1, float* __restrict__ acc2, int N)
{
    int t = blockIdx.x * blockDim.x + threadIdx.x;
    int idx = t / 12, c = t % 12;
    if (idx >= 2 * N) return;
    bool is2 = idx >= N;
    int node = is2 ? idx - N : idx;
    const int*   src = is2 ? src2 : src1;
    const float* nrm = is2 ? norm2 : norm1;

    int start = offs[idx];
    int deg   = cnt[idx];
    float a[8];
    #pragma unroll
    for (int j = 0; j < 8; ++j) a[j] = 0.f;

    for (int k = 0; k < deg; ++k) {
        int e = eid[start + k];
        int s = src[e];
        float nv = nrm[s];
        uint4 raw = *reinterpret_cast<const uint4*>(linb + (size_t)s * HIDF + c * 8);
        a[0] = fmaf(bf2f(raw.x & 0xffffu), nv, a[0]);
        a[1] = fmaf(bf2f(raw.x >> 16),     nv, a[1]);
        a[2] = fmaf(bf2f(raw.y & 0xffffu), nv, a[2]);
        a[3] = fmaf(bf2f(raw.y >> 16),     nv, a[3]);
        a[4] = fmaf(bf2f(raw.z & 0xffffu), nv, a[4]);
        a[5] = fmaf(bf2f(raw.z >> 16),     nv, a[5]);
        a[6] = fmaf(bf2f(raw.w & 0xffffu), nv, a[6]);
        a[7] = fmaf(bf2f(raw.w >> 16),     nv, a[7]);
    }
    float* ap = (is2 ? acc2 : acc1) + (size_t)node * HIDF + c * 8;
    float4 o0; o0.x = a[0]; o0.y = a[1]; o0.z = a[2]; o0.w = a[3];
    float4 o1; o1.x = a[4]; o1.y = a[5]; o1.z = a[6]; o1.w = a[7];
    *reinterpret_cast<float4*>(ap)     = o0;
    *reinterpret_cast<float4*>(ap + 4) = o1;
}

// ---------- comb stage 1: attention weights + comb_bf16 = s1*acc1 + s2*acc2 ----------
// 4 threads per node, each handles 24 features
__global__ __launch_bounds__(256) void comb_c1(
    const float* __restrict__ acc1, const float* __restrict__ acc2,
    const float* __restrict__ norm1, const float* __restrict__ norm2,
    const float* __restrict__ ai,
    const float* __restrict__ W_ar, const float* __restrict__ b_ar,
    unsigned short* __restrict__ combb, int N)
{
    int t = blockIdx.x * 256 + threadIdx.x;
    int n = t >> 2, q = t & 3;
    if (n >= N) return;

    const float4* r1 = reinterpret_cast<const float4*>(acc1 + (size_t)n * HIDF + q * 24);
    const float4* r2 = reinterpret_cast<const float4*>(acc2 + (size_t)n * HIDF + q * 24);
    float4 v1[6], v2[6];
    float d1 = 0.f, d2 = 0.f;
    #pragma unroll
    for (int c = 0; c < 6; ++c) {
        v1[c] = r1[c]; v2[c] = r2[c];
        const float* w = W_ar + q * 24 + c * 4;
        d1 = fmaf(v1[c].x, w[0], d1); d1 = fmaf(v1[c].y, w[1], d1);
        d1 = fmaf(v1[c].z, w[2], d1); d1 = fmaf(v1[c].w, w[3], d1);
        d2 = fmaf(v2[c].x, w[0], d2); d2 = fmaf(v2[c].y, w[1], d2);
        d2 = fmaf(v2[c].z, w[2], d2); d2 = fmaf(v2[c].w, w[3], d2);
    }
    d1 += __shfl_xor(d1, 1); d1 += __shfl_xor(d1, 2);
    d2 += __shfl_xor(d2, 1); d2 += __shfl_xor(d2, 2);

    float n1 = norm1[n], n2 = norm2[n], aiv = ai[n], br = b_ar[0];
    float x1 = aiv + n1 * d1 + br;
    float x2 = aiv + n2 * d2 + br;
    float l1 = x1 >= 0.f ? x1 : 0.2f * x1;
    float l2 = x2 >= 0.f ? x2 : 0.2f * x2;
    float e1 = fminf(fmaxf(__expf(l1), -10.f), 10.f);
    float e2 = fminf(fmaxf(__expf(l2), -10.f), 10.f);
    float inv = 1.f / (e1 + e2);
    float s1 = e1 * inv * n1;
    float s2 = e2 * inv * n2;

    unsigned short ob[24];
    #pragma unroll
    for (int c = 0; c < 6; ++c) {
        ob[c*4+0] = (unsigned short)f2bf(s1 * v1[c].x + s2 * v2[c].x);
        ob[c*4+1] = (unsigned short)f2bf(s1 * v1[c].y + s2 * v2[c].y);
        ob[c*4+2] = (unsigned short)f2bf(s1 * v1[c].z + s2 * v2[c].z);
        ob[c*4+3] = (unsigned short)f2bf(s1 * v1[c].w + s2 * v2[c].w);
    }
    uint4* op = reinterpret_cast<uint4*>(combb + (size_t)n * HIDF + q * 24);
    const uint4* ip = reinterpret_cast<const uint4*>(ob);
    op[0] = ip[0]; op[1] = ip[1]; op[2] = ip[2];
}

// ---------- GEMM2: out = comb_bf16 @ W_fc.T + b_fc ----------
__global__ __launch_bounds__(256) void gemm_fc(
    const unsigned short* __restrict__ combb, const short* __restrict__ Bp2,
    const float* __restrict__ b_fc, float* __restrict__ out, int N)
{
    __shared__ short Bs[3 * 6 * 64 * 8];   // 18 KiB
    {
        const uint4* gsrc = reinterpret_cast<const uint4*>(Bp2);
        uint4* ldst = reinterpret_cast<uint4*>(Bs);
        for (int i = threadIdx.x; i < 3 * 6 * 64 * 8 / 8; i += 256) ldst[i] = gsrc[i];
    }
    __syncthreads();

    int lane = threadIdx.x & 63;
    int wid = threadIdx.x >> 6;
    int m0 = blockIdx.x * 64 + wid * 16;
    int arow = m0 + (lane & 15);
    int rc = arow < N ? arow : N - 1;
    const unsigned short* crow = combb + (size_t)rc * HIDF;
    int koff = (lane >> 4) << 3;

    f32x4 acc[6];
    #pragma unroll
    for (int nt = 0; nt < 6; ++nt) acc[nt] = (f32x4){0.f, 0.f, 0.f, 0.f};

    #pragma unroll
    for (int kt = 0; kt < 3; ++kt) {
        bf16x8 a8 = *reinterpret_cast<const bf16x8*>(crow + kt * 32 + koff);
        #pragma unroll
        for (int nt = 0; nt < 6; ++nt) {
            bf16x8 b8 = *reinterpret_cast<const bf16x8*>(&Bs[((kt * 6 + nt) * 64 + lane) * 8]);
            acc[nt] = __builtin_amdgcn_mfma_f32_16x16x32_bf16(a8, b8, acc[nt], 0, 0, 0);
        }
    }

    int rbase = m0 + ((lane >> 4) << 2);
    #pragma unroll
    for (int nt = 0; nt < 6; ++nt) {
        int col = nt * 16 + (lane & 15);
        float bf = b_fc[col];
        #pragma unroll
        for (int r = 0; r < 4; ++r) {
            int rrow = rbase + r;
            if (rrow < N) out[(size_t)rrow * HIDF + col] = acc[nt][r] + bf;
        }
    }
}

extern "C" void kernel_launch(void* const* d_in, const int* in_sizes, int n_in,
                              void* d_out, int out_size, void* d_ws, size_t ws_size,
                              hipStream_t stream) {
    const float* h     = (const float*)d_in[0];
    const float* norm1 = (const float*)d_in[1];
    const float* norm2 = (const float*)d_in[2];
    const int*   src1  = (const int*)d_in[3];
    const int*   dst1  = (const int*)d_in[4];
    const int*   src2  = (const int*)d_in[5];
    const int*   dst2  = (const int*)d_in[6];
    const float* W_lin = (const float*)d_in[7];
    const float* b_lin = (const float*)d_in[8];
    const float* W_fc  = (const float*)d_in[9];
    const float* b_fc  = (const float*)d_in[10];
    const float* W_al  = (const float*)d_in[11];
    const float* b_al  = (const float*)d_in[12];
    const float* W_ar  = (const float*)d_in[13];
    const float* b_ar  = (const float*)d_in[14];

    const int N = in_sizes[1];
    const int E = in_sizes[3];

    char* p = (char*)d_ws;
    auto alloc = [&](size_t bytes) {
        char* r = p;
        p += (bytes + 255) & ~(size_t)255;
        return r;
    };
    short* Bp1  = (short*)alloc((size_t)8 * 6 * 64 * 8 * 2);
    short* Bp2  = (short*)alloc((size_t)3 * 6 * 64 * 8 * 2);
    float* ai   = (float*)alloc((size_t)N * 4);
    unsigned short* linb  = (unsigned short*)alloc((size_t)N * HIDF * 2);
    unsigned short* combb = (unsigned short*)alloc((size_t)N * HIDF * 2);
    float* acc1 = (float*)alloc((size_t)N * HIDF * 4);
    float* acc2 = (float*)alloc((size_t)N * HIDF * 4);
    int*   cnt    = (int*)alloc((size_t)2 * N * 4);
    int*   offs   = (int*)alloc((size_t)2 * N * 4);
    int*   cursor = (int*)alloc((size_t)2 * N * 4);
    int*   eid    = (int*)alloc((size_t)2 * E * 4);
    int*   bsum   = (int*)alloc(1024 * 4);

    const int n2N = 2 * N;
    const int nb  = (n2N + 255) / 256;

    hipMemsetAsync(cnt, 0, (size_t)n2N * 4, stream);

    pack_weights<<<(8 * 6 * 64 + 3 * 6 * 64 + 255) / 256, 256, 0, stream>>>(W_lin, W_fc, Bp1, Bp2);

    hist_kernel<<<(2 * E + 255) / 256, 256, 0, stream>>>(dst1, dst2, cnt, E, N);
    scan_part<<<nb, 256, 0, stream>>>(cnt, offs, bsum, n2N);
    scan_top<<<1, 512, 0, stream>>>(bsum, nb);
    scan_add<<<nb, 256, 0, stream>>>(offs, cursor, bsum, n2N);
    scatter_kernel<<<(2 * E + 255) / 256, 256, 0, stream>>>(dst1, dst2, cursor, eid, E, N);

    int mblocks = (N + 63) / 64;
    gemm_lin<<<mblocks, 256, 0, stream>>>(h, Bp1, b_lin, W_al, b_al, linb, ai, N);

    int aggThreads = n2N * 12;
    agg_csr<<<(aggThreads + 255) / 256, 256, 0, stream>>>(
        linb, norm1, norm2, src1, src2, offs, cnt, eid, acc1, acc2, N);

    comb_c1<<<(4 * N + 255) / 256, 256, 0, stream>>>(
        acc1, acc2, norm1, norm2, ai, W_ar, b_ar, combb, N);

    gemm_fc<<<mblocks, 256, 0, stream>>>(combb, Bp2, b_fc, (float*)d_out, N);
}

// Round 4
// 215.227 us; speedup vs baseline: 10.5970x; 1.5106x over previous
//
#include <hip/hip_runtime.h>
#include <hip/hip_bf16.h>

#define HIDF 96
#define INF 256
#define CNT_STRIDE 16   // one counter per 64B line

typedef short bf16x8 __attribute__((ext_vector_type(8)));
typedef float f32x4 __attribute__((ext_vector_type(4)));

static __device__ inline short f2bf(float f) {
    __hip_bfloat16 b = __float2bfloat16(f);
    short s;
    __builtin_memcpy(&s, &b, 2);
    return s;
}
static __device__ inline float bf2f(unsigned u) {
    union { unsigned x; float f; } v;
    v.x = u << 16;
    return v.f;
}

// ---------- pack W_lin and W_fc into MFMA B-fragment layout ----------
__global__ __launch_bounds__(256) void pack_weights(
    const float* __restrict__ W_lin, const float* __restrict__ W_fc,
    short* __restrict__ Bp1, short* __restrict__ Bp2)
{
    int t = blockIdx.x * 256 + threadIdx.x;
    if (t < 8 * 6 * 64) {
        int kt = t / (6 * 64), rem = t % (6 * 64), nt = rem / 64, l = rem % 64;
        int n = nt * 16 + (l & 15);
        int k0 = kt * 32 + ((l >> 4) << 3);
        short v[8];
        #pragma unroll
        for (int j = 0; j < 8; ++j) v[j] = f2bf(W_lin[n * INF + k0 + j]);
        #pragma unroll
        for (int j = 0; j < 8; ++j) Bp1[(size_t)t * 8 + j] = v[j];
    } else if (t < 8 * 6 * 64 + 3 * 6 * 64) {
        int u = t - 8 * 6 * 64;
        int kt = u / (6 * 64), rem = u % (6 * 64), nt = rem / 64, l = rem % 64;
        int n = nt * 16 + (l & 15);
        int k0 = kt * 32 + ((l >> 4) << 3);
        short v[8];
        #pragma unroll
        for (int j = 0; j < 8; ++j) v[j] = f2bf(W_fc[n * HIDF + k0 + j]);
        #pragma unroll
        for (int j = 0; j < 8; ++j) Bp2[(size_t)u * 8 + j] = v[j];
    }
}

// ---------- rank: per-edge rank within its dst, padded counters ----------
__global__ __launch_bounds__(256) void rank_kernel(
    const int* __restrict__ dst1, const int* __restrict__ dst2,
    int* __restrict__ cntp, int* __restrict__ rank, int E, int N)
{
    int t = blockIdx.x * blockDim.x + threadIdx.x;
    if (t >= 2 * E) return;
    int key = (t < E) ? dst1[t] : N + dst2[t - E];
    rank[t] = atomicAdd(&cntp[(size_t)key * CNT_STRIDE], 1);
}

// ---------- scan stage 1: per-block exclusive scan over padded counters ----------
__global__ __launch_bounds__(256) void scan_part(
    const int* __restrict__ cntp, int* __restrict__ offs, int* __restrict__ bsum, int n)
{
    __shared__ int s[256];
    int i = blockIdx.x * 256 + threadIdx.x;
    int v = (i < n) ? cntp[(size_t)i * CNT_STRIDE] : 0;
    s[threadIdx.x] = v;
    __syncthreads();
    for (int d = 1; d < 256; d <<= 1) {
        int t = (threadIdx.x >= d) ? s[threadIdx.x - d] : 0;
        __syncthreads();
        s[threadIdx.x] += t;
        __syncthreads();
    }
    int inc = s[threadIdx.x];
    if (i < n) offs[i] = inc - v;
    if (threadIdx.x == 255) bsum[blockIdx.x] = inc;
}

__global__ __launch_bounds__(512) void scan_top(int* __restrict__ bsum, int nb)
{
    __shared__ int s[512];
    int i = threadIdx.x;
    int v = (i < nb) ? bsum[i] : 0;
    s[i] = v;
    __syncthreads();
    for (int d = 1; d < 512; d <<= 1) {
        int t = (i >= d) ? s[i - d] : 0;
        __syncthreads();
        s[i] += t;
        __syncthreads();
    }
    if (i < nb) bsum[i] = s[i] - v;
}

__global__ __launch_bounds__(256) void scan_add(
    int* __restrict__ offs, const int* __restrict__ bsum, int n)
{
    int i = blockIdx.x * 256 + threadIdx.x;
    if (i >= n) return;
    offs[i] += bsum[blockIdx.x];
}

// ---------- place: p = offs[key] + rank[t]; payload[p] = {src, norm[src]} ----------
__global__ __launch_bounds__(256) void place_kernel(
    const int* __restrict__ src1, const int* __restrict__ dst1,
    const int* __restrict__ src2, const int* __restrict__ dst2,
    const float* __restrict__ norm1, const float* __restrict__ norm2,
    const int* __restrict__ offs, const int* __restrict__ rank,
    int2* __restrict__ payload, int E, int N)
{
    int t = blockIdx.x * blockDim.x + threadIdx.x;
    if (t >= 2 * E) return;
    int s, key; float nv;
    if (t < E) {
        s = src1[t]; key = dst1[t]; nv = norm1[s];
    } else {
        int e = t - E;
        s = src2[e]; key = N + dst2[e]; nv = norm2[s];
    }
    int p = offs[key] + rank[t];
    payload[p] = make_int2(s, __float_as_int(nv));
}

// ---------- GEMM1: lin_bf16 = bf16(h) @ W_lin.T + b_lin ; ai = W_al . lin + b_al ----------
__global__ __launch_bounds__(256) void gemm_lin(
    const float* __restrict__ h, const short* __restrict__ Bp1,
    const float* __restrict__ b_lin, const float* __restrict__ W_al,
    const float* __restrict__ b_al,
    unsigned short* __restrict__ linb, float* __restrict__ ai, int N)
{
    __shared__ short Bs[8 * 6 * 64 * 8];   // 48 KiB
    {
        const uint4* gsrc = reinterpret_cast<const uint4*>(Bp1);
        uint4* ldst = reinterpret_cast<uint4*>(Bs);
        for (int i = threadIdx.x; i < 8 * 6 * 64 * 8 / 8; i += 256) ldst[i] = gsrc[i];
    }
    __syncthreads();

    int lane = threadIdx.x & 63;
    int wid = threadIdx.x >> 6;
    int m0 = blockIdx.x * 64 + wid * 16;
    int arow = m0 + (lane & 15);
    int rc = arow < N ? arow : N - 1;
    const float* hrow = h + (size_t)rc * INF;
    int koff = (lane >> 4) << 3;

    f32x4 acc[6];
    #pragma unroll
    for (int nt = 0; nt < 6; ++nt) acc[nt] = (f32x4){0.f, 0.f, 0.f, 0.f};

    for (int kt = 0; kt < 8; ++kt) {
        const float4* hp = reinterpret_cast<const float4*>(hrow + kt * 32 + koff);
        float4 f0 = hp[0], f1 = hp[1];
        bf16x8 a8;
        a8[0] = f2bf(f0.x); a8[1] = f2bf(f0.y); a8[2] = f2bf(f0.z); a8[3] = f2bf(f0.w);
        a8[4] = f2bf(f1.x); a8[5] = f2bf(f1.y); a8[6] = f2bf(f1.z); a8[7] = f2bf(f1.w);
        #pragma unroll
        for (int nt = 0; nt < 6; ++nt) {
            bf16x8 b8 = *reinterpret_cast<const bf16x8*>(&Bs[((kt * 6 + nt) * 64 + lane) * 8]);
            acc[nt] = __builtin_amdgcn_mfma_f32_16x16x32_bf16(a8, b8, acc[nt], 0, 0, 0);
        }
    }

    float pai[4] = {0.f, 0.f, 0.f, 0.f};
    int rbase = m0 + ((lane >> 4) << 2);
    #pragma unroll
    for (int nt = 0; nt < 6; ++nt) {
        int col = nt * 16 + (lane & 15);
        float bl = b_lin[col];
        float wal = W_al[col];
        #pragma unroll
        for (int r = 0; r < 4; ++r) {
            float v = acc[nt][r] + bl;
            int rrow = rbase + r;
            if (rrow < N) linb[(size_t)rrow * HIDF + col] = (unsigned short)f2bf(v);
            pai[r] = fmaf(wal, v, pai[r]);
        }
    }
    #pragma unroll
    for (int r = 0; r < 4; ++r) {
        float p = pai[r];
        p += __shfl_xor(p, 1);
        p += __shfl_xor(p, 2);
        p += __shfl_xor(p, 4);
        p += __shfl_xor(p, 8);
        int rrow = rbase + r;
        if ((lane & 15) == 0 && rrow < N) ai[rrow] = p + b_al[0];
    }
}

// ---------- agg: CSR aggregation over bf16 lin table, payload = {src, norm} ----------
__global__ __launch_bounds__(256) void agg_csr(
    const unsigned short* __restrict__ linb,
    const int* __restrict__ offs, const int2* __restrict__ payload,
    float* __restrict__ acc1, float* __restrict__ acc2, int N, int totE)
{
    int t = blockIdx.x * blockDim.x + threadIdx.x;
    int idx = t / 12, c = t % 12;
    if (idx >= 2 * N) return;

    int start = offs[idx];
    int end = (idx == 2 * N - 1) ? totE : offs[idx + 1];

    float a[8];
    #pragma unroll
    for (int j = 0; j < 8; ++j) a[j] = 0.f;

    for (int k = start; k < end; ++k) {
        int2 pl = payload[k];                 // broadcast within 12-group
        float nv = __int_as_float(pl.y);
        uint4 raw = *reinterpret_cast<const uint4*>(linb + (size_t)pl.x * HIDF + c * 8);
        a[0] = fmaf(bf2f(raw.x & 0xffffu), nv, a[0]);
        a[1] = fmaf(bf2f(raw.x >> 16),     nv, a[1]);
        a[2] = fmaf(bf2f(raw.y & 0xffffu), nv, a[2]);
        a[3] = fmaf(bf2f(raw.y >> 16),     nv, a[3]);
        a[4] = fmaf(bf2f(raw.z & 0xffffu), nv, a[4]);
        a[5] = fmaf(bf2f(raw.z >> 16),     nv, a[5]);
        a[6] = fmaf(bf2f(raw.w & 0xffffu), nv, a[6]);
        a[7] = fmaf(bf2f(raw.w >> 16),     nv, a[7]);
    }
    bool is2 = idx >= N;
    int node = is2 ? idx - N : idx;
    float* ap = (is2 ? acc2 : acc1) + (size_t)node * HIDF + c * 8;
    float4 o0; o0.x = a[0]; o0.y = a[1]; o0.z = a[2]; o0.w = a[3];
    float4 o1; o1.x = a[4]; o1.y = a[5]; o1.z = a[6]; o1.w = a[7];
    *reinterpret_cast<float4*>(ap)     = o0;
    *reinterpret_cast<float4*>(ap + 4) = o1;
}

// ---------- comb stage 1: attention weights + comb_bf16 ----------
__global__ __launch_bounds__(256) void comb_c1(
    const float* __restrict__ acc1, const float* __restrict__ acc2,
    const float* __restrict__ norm1, const float* __restrict__ norm2,
    const float* __restrict__ ai,
    const float* __restrict__ W_ar, const float* __restrict__ b_ar,
    unsigned short* __restrict__ combb, int N)
{
    int t = blockIdx.x * 256 + threadIdx.x;
    int n = t >> 2, q = t & 3;
    if (n >= N) return;

    const float4* r1 = reinterpret_cast<const float4*>(acc1 + (size_t)n * HIDF + q * 24);
    const float4* r2 = reinterpret_cast<const float4*>(acc2 + (size_t)n * HIDF + q * 24);
    float4 v1[6], v2[6];
    float d1 = 0.f, d2 = 0.f;
    #pragma unroll
    for (int c = 0; c < 6; ++c) {
        v1[c] = r1[c]; v2[c] = r2[c];
        const float* w = W_ar + q * 24 + c * 4;
        d1 = fmaf(v1[c].x, w[0], d1); d1 = fmaf(v1[c].y, w[1], d1);
        d1 = fmaf(v1[c].z, w[2], d1); d1 = fmaf(v1[c].w, w[3], d1);
        d2 = fmaf(v2[c].x, w[0], d2); d2 = fmaf(v2[c].y, w[1], d2);
        d2 = fmaf(v2[c].z, w[2], d2); d2 = fmaf(v2[c].w, w[3], d2);
    }
    d1 += __shfl_xor(d1, 1); d1 += __shfl_xor(d1, 2);
    d2 += __shfl_xor(d2, 1); d2 += __shfl_xor(d2, 2);

    float n1 = norm1[n], n2 = norm2[n], aiv = ai[n], br = b_ar[0];
    float x1 = aiv + n1 * d1 + br;
    float x2 = aiv + n2 * d2 + br;
    float l1 = x1 >= 0.f ? x1 : 0.2f * x1;
    float l2 = x2 >= 0.f ? x2 : 0.2f * x2;
    float e1 = fminf(fmaxf(__expf(l1), -10.f), 10.f);
    float e2 = fminf(fmaxf(__expf(l2), -10.f), 10.f);
    float inv = 1.f / (e1 + e2);
    float s1 = e1 * inv * n1;
    float s2 = e2 * inv * n2;

    unsigned short ob[24];
    #pragma unroll
    for (int c = 0; c < 6; ++c) {
        ob[c*4+0] = (unsigned short)f2bf(s1 * v1[c].x + s2 * v2[c].x);
        ob[c*4+1] = (unsigned short)f2bf(s1 * v1[c].y + s2 * v2[c].y);
        ob[c*4+2] = (unsigned short)f2bf(s1 * v1[c].z + s2 * v2[c].z);
        ob[c*4+3] = (unsigned short)f2bf(s1 * v1[c].w + s2 * v2[c].w);
    }
    uint4* op = reinterpret_cast<uint4*>(combb + (size_t)n * HIDF + q * 24);
    const uint4* ip = reinterpret_cast<const uint4*>(ob);
    op[0] = ip[0]; op[1] = ip[1]; op[2] = ip[2];
}

// ---------- GEMM2: out = comb_bf16 @ W_fc.T + b_fc ----------
__global__ __launch_bounds__(256) void gemm_fc(
    const unsigned short* __restrict__ combb, const short* __restrict__ Bp2,
    const float* __restrict__ b_fc, float* __restrict__ out, int N)
{
    __shared__ short Bs[3 * 6 * 64 * 8];   // 18 KiB
    {
        const uint4* gsrc = reinterpret_cast<const uint4*>(Bp2);
        uint4* ldst = reinterpret_cast<uint4*>(Bs);
        for (int i = threadIdx.x; i < 3 * 6 * 64 * 8 / 8; i += 256) ldst[i] = gsrc[i];
    }
    __syncthreads();

    int lane = threadIdx.x & 63;
    int wid = threadIdx.x >> 6;
    int m0 = blockIdx.x * 64 + wid * 16;
    int arow = m0 + (lane & 15);
    int rc = arow < N ? arow : N - 1;
    const unsigned short* crow = combb + (size_t)rc * HIDF;
    int koff = (lane >> 4) << 3;

    f32x4 acc[6];
    #pragma unroll
    for (int nt = 0; nt < 6; ++nt) acc[nt] = (f32x4){0.f, 0.f, 0.f, 0.f};

    #pragma unroll
    for (int kt = 0; kt < 3; ++kt) {
        bf16x8 a8 = *reinterpret_cast<const bf16x8*>(crow + kt * 32 + koff);
        #pragma unroll
        for (int nt = 0; nt < 6; ++nt) {
            bf16x8 b8 = *reinterpret_cast<const bf16x8*>(&Bs[((kt * 6 + nt) * 64 + lane) * 8]);
            acc[nt] = __builtin_amdgcn_mfma_f32_16x16x32_bf16(a8, b8, acc[nt], 0, 0, 0);
        }
    }

    int rbase = m0 + ((lane >> 4) << 2);
    #pragma unroll
    for (int nt = 0; nt < 6; ++nt) {
        int col = nt * 16 + (lane & 15);
        float bf = b_fc[col];
        #pragma unroll
        for (int r = 0; r < 4; ++r) {
            int rrow = rbase + r;
            if (rrow < N) out[(size_t)rrow * HIDF + col] = acc[nt][r] + bf;
        }
    }
}

extern "C" void kernel_launch(void* const* d_in, const int* in_sizes, int n_in,
                              void* d_out, int out_size, void* d_ws, size_t ws_size,
                              hipStream_t stream) {
    const float* h     = (const float*)d_in[0];
    const float* norm1 = (const float*)d_in[1];
    const float* norm2 = (const float*)d_in[2];
    const int*   src1  = (const int*)d_in[3];
    const int*   dst1  = (const int*)d_in[4];
    const int*   src2  = (const int*)d_in[5];
    const int*   dst2  = (const int*)d_in[6];
    const float* W_lin = (const float*)d_in[7];
    const float* b_lin = (const float*)d_in[8];
    const float* W_fc  = (const float*)d_in[9];
    const float* b_fc  = (const float*)d_in[10];
    const float* W_al  = (const float*)d_in[11];
    const float* b_al  = (const float*)d_in[12];
    const float* W_ar  = (const float*)d_in[13];
    const float* b_ar  = (const float*)d_in[14];

    const int N = in_sizes[1];
    const int E = in_sizes[3];

    char* p = (char*)d_ws;
    auto alloc = [&](size_t bytes) {
        char* r = p;
        p += (bytes + 255) & ~(size_t)255;
        return r;
    };
    short* Bp1  = (short*)alloc((size_t)8 * 6 * 64 * 8 * 2);
    short* Bp2  = (short*)alloc((size_t)3 * 6 * 64 * 8 * 2);
    float* ai   = (float*)alloc((size_t)N * 4);
    unsigned short* linb  = (unsigned short*)alloc((size_t)N * HIDF * 2);
    unsigned short* combb = (unsigned short*)alloc((size_t)N * HIDF * 2);
    float* acc1 = (float*)alloc((size_t)N * HIDF * 4);
    float* acc2 = (float*)alloc((size_t)N * HIDF * 4);
    int*   cntp = (int*)alloc((size_t)2 * N * CNT_STRIDE * 4);   // padded counters
    int*   offs = (int*)alloc((size_t)2 * N * 4);
    int*   rank = (int*)alloc((size_t)2 * E * 4);
    int2*  payload = (int2*)alloc((size_t)2 * E * 8);
    int*   bsum = (int*)alloc(1024 * 4);

    const int n2N = 2 * N;
    const int nb  = (n2N + 255) / 256;

    hipMemsetAsync(cntp, 0, (size_t)n2N * CNT_STRIDE * 4, stream);

    pack_weights<<<(8 * 6 * 64 + 3 * 6 * 64 + 255) / 256, 256, 0, stream>>>(W_lin, W_fc, Bp1, Bp2);

    rank_kernel<<<(2 * E + 255) / 256, 256, 0, stream>>>(dst1, dst2, cntp, rank, E, N);
    scan_part<<<nb, 256, 0, stream>>>(cntp, offs, bsum, n2N);
    scan_top<<<1, 512, 0, stream>>>(bsum, nb);
    scan_add<<<nb, 256, 0, stream>>>(offs, bsum, n2N);
    place_kernel<<<(2 * E + 255) / 256, 256, 0, stream>>>(
        src1, dst1, src2, dst2, norm1, norm2, offs, rank, payload, E, N);

    int mblocks = (N + 63) / 64;
    gemm_lin<<<mblocks, 256, 0, stream>>>(h, Bp1, b_lin, W_al, b_al, linb, ai, N);

    int aggThreads = n2N * 12;
    agg_csr<<<(aggThreads + 255) / 256, 256, 0, stream>>>(
        linb, offs, payload, acc1, acc2, N, 2 * E);

    comb_c1<<<(4 * N + 255) / 256, 256, 0, stream>>>(
        acc1, acc2, norm1, norm2, ai, W_ar, b_ar, combb, N);

    gemm_fc<<<mblocks, 256, 0, stream>>>(combb, Bp2, b_fc, (float*)d_out, N);
}

// Round 6
// 209.451 us; speedup vs baseline: 10.8892x; 1.0276x over previous
//
#include <hip/hip_runtime.h>
#include <hip/hip_bf16.h>

#define HIDF 96
#define INF 256
#define CNT_STRIDE 16   // one counter per 64B line

typedef short bf16x8 __attribute__((ext_vector_type(8)));
typedef float f32x4 __attribute__((ext_vector_type(4)));

static __device__ inline short f2bf(float f) {
    __hip_bfloat16 b = __float2bfloat16(f);
    short s;
    __builtin_memcpy(&s, &b, 2);
    return s;
}
static __device__ inline float bf2f(unsigned u) {
    union { unsigned x; float f; } v;
    v.x = u << 16;
    return v.f;
}

// ---------- fused: pack weights (blocks 0,1) + rank with 4-edge ILP (blocks 2+) ----------
__global__ __launch_bounds__(256) void prep_rank(
    const float* __restrict__ W_lin, const float* __restrict__ W_fc,
    short* __restrict__ Bp1, short* __restrict__ Bp2,
    const int* __restrict__ dst1, const int* __restrict__ dst2,
    int* __restrict__ cntp, int* __restrict__ rank, int E, int N)
{
    if (blockIdx.x == 0) {
        for (int t = threadIdx.x; t < 8 * 6 * 64; t += 256) {
            int kt = t / (6 * 64), rem = t % (6 * 64), nt = rem / 64, l = rem % 64;
            int n = nt * 16 + (l & 15);
            int k0 = kt * 32 + ((l >> 4) << 3);
            short v[8];
            #pragma unroll
            for (int j = 0; j < 8; ++j) v[j] = f2bf(W_lin[n * INF + k0 + j]);
            #pragma unroll
            for (int j = 0; j < 8; ++j) Bp1[(size_t)t * 8 + j] = v[j];
        }
        return;
    }
    if (blockIdx.x == 1) {
        for (int t = threadIdx.x; t < 3 * 6 * 64; t += 256) {
            int kt = t / (6 * 64), rem = t % (6 * 64), nt = rem / 64, l = rem % 64;
            int n = nt * 16 + (l & 15);
            int k0 = kt * 32 + ((l >> 4) << 3);
            short v[8];
            #pragma unroll
            for (int j = 0; j < 8; ++j) v[j] = f2bf(W_fc[n * HIDF + k0 + j]);
            #pragma unroll
            for (int j = 0; j < 8; ++j) Bp2[(size_t)t * 8 + j] = v[j];
        }
        return;
    }
    // rank: 4 edges per thread, 4 atomic-returns in flight
    int base = (blockIdx.x - 2) * 1024 + threadIdx.x;
    int tot = 2 * E;
    #pragma unroll
    for (int i = 0; i < 4; ++i) {
        int e = base + i * 256;
        if (e < tot) {
            int key = (e < E) ? dst1[e] : N + dst2[e - E];
            rank[e] = atomicAdd(&cntp[(size_t)key * CNT_STRIDE], 1);
        }
    }
}

// ---------- scan stage 1 ----------
__global__ __launch_bounds__(256) void scan_part(
    const int* __restrict__ cntp, int* __restrict__ offs, int* __restrict__ bsum, int n)
{
    __shared__ int s[256];
    int i = blockIdx.x * 256 + threadIdx.x;
    int v = (i < n) ? cntp[(size_t)i * CNT_STRIDE] : 0;
    s[threadIdx.x] = v;
    __syncthreads();
    for (int d = 1; d < 256; d <<= 1) {
        int t = (threadIdx.x >= d) ? s[threadIdx.x - d] : 0;
        __syncthreads();
        s[threadIdx.x] += t;
        __syncthreads();
    }
    int inc = s[threadIdx.x];
    if (i < n) offs[i] = inc - v;
    if (threadIdx.x == 255) bsum[blockIdx.x] = inc;
}

__global__ __launch_bounds__(512) void scan_top(int* __restrict__ bsum, int nb)
{
    __shared__ int s[512];
    int i = threadIdx.x;
    int v = (i < nb) ? bsum[i] : 0;
    s[i] = v;
    __syncthreads();
    for (int d = 1; d < 512; d <<= 1) {
        int t = (i >= d) ? s[i - d] : 0;
        __syncthreads();
        s[i] += t;
        __syncthreads();
    }
    if (i < nb) bsum[i] = s[i] - v;
}

__global__ __launch_bounds__(256) void scan_add(
    int* __restrict__ offs, const int* __restrict__ bsum, int n)
{
    int i = blockIdx.x * 256 + threadIdx.x;
    if (i >= n) return;
    offs[i] += bsum[blockIdx.x];
}

// ---------- place: payload[p] = src only (4B) ----------
__global__ __launch_bounds__(256) void place_kernel(
    const int* __restrict__ src1, const int* __restrict__ dst1,
    const int* __restrict__ src2, const int* __restrict__ dst2,
    const int* __restrict__ offs, const int* __restrict__ rank,
    int* __restrict__ payload, int E, int N)
{
    int t = blockIdx.x * blockDim.x + threadIdx.x;
    if (t >= 2 * E) return;
    int s, key;
    if (t < E) { s = src1[t]; key = dst1[t]; }
    else       { int e = t - E; s = src2[e]; key = N + dst2[e]; }
    int p = offs[key] + rank[t];
    payload[p] = s;
}

// ---------- GEMM1: lin_bf16 = bf16(h) @ W_lin.T + b_lin ; ai = W_al . lin + b_al ----------
__global__ __launch_bounds__(256) void gemm_lin(
    const float* __restrict__ h, const short* __restrict__ Bp1,
    const float* __restrict__ b_lin, const float* __restrict__ W_al,
    const float* __restrict__ b_al,
    unsigned short* __restrict__ linb, float* __restrict__ ai, int N)
{
    __shared__ short Bs[8 * 6 * 64 * 8];   // 48 KiB
    {
        const uint4* gsrc = reinterpret_cast<const uint4*>(Bp1);
        uint4* ldst = reinterpret_cast<uint4*>(Bs);
        for (int i = threadIdx.x; i < 8 * 6 * 64 * 8 / 8; i += 256) ldst[i] = gsrc[i];
    }
    __syncthreads();

    int lane = threadIdx.x & 63;
    int wid = threadIdx.x >> 6;
    int m0 = blockIdx.x * 64 + wid * 16;
    int arow = m0 + (lane & 15);
    int rc = arow < N ? arow : N - 1;
    const float* hrow = h + (size_t)rc * INF;
    int koff = (lane >> 4) << 3;

    f32x4 acc[6];
    #pragma unroll
    for (int nt = 0; nt < 6; ++nt) acc[nt] = (f32x4){0.f, 0.f, 0.f, 0.f};

    for (int kt = 0; kt < 8; ++kt) {
        const float4* hp = reinterpret_cast<const float4*>(hrow + kt * 32 + koff);
        float4 f0 = hp[0], f1 = hp[1];
        bf16x8 a8;
        a8[0] = f2bf(f0.x); a8[1] = f2bf(f0.y); a8[2] = f2bf(f0.z); a8[3] = f2bf(f0.w);
        a8[4] = f2bf(f1.x); a8[5] = f2bf(f1.y); a8[6] = f2bf(f1.z); a8[7] = f2bf(f1.w);
        #pragma unroll
        for (int nt = 0; nt < 6; ++nt) {
            bf16x8 b8 = *reinterpret_cast<const bf16x8*>(&Bs[((kt * 6 + nt) * 64 + lane) * 8]);
            acc[nt] = __builtin_amdgcn_mfma_f32_16x16x32_bf16(a8, b8, acc[nt], 0, 0, 0);
        }
    }

    float pai[4] = {0.f, 0.f, 0.f, 0.f};
    int rbase = m0 + ((lane >> 4) << 2);
    #pragma unroll
    for (int nt = 0; nt < 6; ++nt) {
        int col = nt * 16 + (lane & 15);
        float bl = b_lin[col];
        float wal = W_al[col];
        #pragma unroll
        for (int r = 0; r < 4; ++r) {
            float v = acc[nt][r] + bl;
            int rrow = rbase + r;
            if (rrow < N) linb[(size_t)rrow * HIDF + col] = (unsigned short)f2bf(v);
            pai[r] = fmaf(wal, v, pai[r]);
        }
    }
    #pragma unroll
    for (int r = 0; r < 4; ++r) {
        float p = pai[r];
        p += __shfl_xor(p, 1);
        p += __shfl_xor(p, 2);
        p += __shfl_xor(p, 4);
        p += __shfl_xor(p, 8);
        int rrow = rbase + r;
        if ((lane & 15) == 0 && rrow < N) ai[rrow] = p + b_al[0];
    }
}

// ---------- agg: CSR aggregation over bf16 lin table ----------
__global__ __launch_bounds__(256) void agg_csr(
    const unsigned short* __restrict__ linb,
    const float* __restrict__ norm1, const float* __restrict__ norm2,
    const int* __restrict__ offs, const int* __restrict__ payload,
    float* __restrict__ acc1, float* __restrict__ acc2, int N, int totE)
{
    int t = blockIdx.x * blockDim.x + threadIdx.x;
    int idx = t / 12, c = t % 12;
    if (idx >= 2 * N) return;

    bool is2 = idx >= N;
    const float* nrm = is2 ? norm2 : norm1;
    int start = offs[idx];
    int end = (idx == 2 * N - 1) ? totE : offs[idx + 1];

    float a[8];
    #pragma unroll
    for (int j = 0; j < 8; ++j) a[j] = 0.f;

    for (int k = start; k < end; ++k) {
        int s = payload[k];                   // broadcast within 12-group
        float nv = nrm[s];                    // broadcast
        uint4 raw = *reinterpret_cast<const uint4*>(linb + (size_t)s * HIDF + c * 8);
        a[0] = fmaf(bf2f(raw.x & 0xffffu), nv, a[0]);
        a[1] = fmaf(bf2f(raw.x >> 16),     nv, a[1]);
        a[2] = fmaf(bf2f(raw.y & 0xffffu), nv, a[2]);
        a[3] = fmaf(bf2f(raw.y >> 16),     nv, a[3]);
        a[4] = fmaf(bf2f(raw.z & 0xffffu), nv, a[4]);
        a[5] = fmaf(bf2f(raw.z >> 16),     nv, a[5]);
        a[6] = fmaf(bf2f(raw.w & 0xffffu), nv, a[6]);
        a[7] = fmaf(bf2f(raw.w >> 16),     nv, a[7]);
    }
    int node = is2 ? idx - N : idx;
    float* ap = (is2 ? acc2 : acc1) + (size_t)node * HIDF + c * 8;
    float4 o0; o0.x = a[0]; o0.y = a[1]; o0.z = a[2]; o0.w = a[3];
    float4 o1; o1.x = a[4]; o1.y = a[5]; o1.z = a[6]; o1.w = a[7];
    *reinterpret_cast<float4*>(ap)     = o0;
    *reinterpret_cast<float4*>(ap + 4) = o1;
}

// ---------- comb stage 1 (R4-proven): attention weights + comb_bf16 ----------
__global__ __launch_bounds__(256) void comb_c1(
    const float* __restrict__ acc1, const float* __restrict__ acc2,
    const float* __restrict__ norm1, const float* __restrict__ norm2,
    const float* __restrict__ ai,
    const float* __restrict__ W_ar, const float* __restrict__ b_ar,
    unsigned short* __restrict__ combb, int N)
{
    int t = blockIdx.x * 256 + threadIdx.x;
    int n = t >> 2, q = t & 3;
    if (n >= N) return;

    const float4* r1 = reinterpret_cast<const float4*>(acc1 + (size_t)n * HIDF + q * 24);
    const float4* r2 = reinterpret_cast<const float4*>(acc2 + (size_t)n * HIDF + q * 24);
    float4 v1[6], v2[6];
    float d1 = 0.f, d2 = 0.f;
    #pragma unroll
    for (int c = 0; c < 6; ++c) {
        v1[c] = r1[c]; v2[c] = r2[c];
        const float* w = W_ar + q * 24 + c * 4;
        d1 = fmaf(v1[c].x, w[0], d1); d1 = fmaf(v1[c].y, w[1], d1);
        d1 = fmaf(v1[c].z, w[2], d1); d1 = fmaf(v1[c].w, w[3], d1);
        d2 = fmaf(v2[c].x, w[0], d2); d2 = fmaf(v2[c].y, w[1], d2);
        d2 = fmaf(v2[c].z, w[2], d2); d2 = fmaf(v2[c].w, w[3], d2);
    }
    d1 += __shfl_xor(d1, 1); d1 += __shfl_xor(d1, 2);
    d2 += __shfl_xor(d2, 1); d2 += __shfl_xor(d2, 2);

    float n1 = norm1[n], n2 = norm2[n], aiv = ai[n], br = b_ar[0];
    float x1 = aiv + n1 * d1 + br;
    float x2 = aiv + n2 * d2 + br;
    float l1 = x1 >= 0.f ? x1 : 0.2f * x1;
    float l2 = x2 >= 0.f ? x2 : 0.2f * x2;
    float e1 = fminf(fmaxf(__expf(l1), -10.f), 10.f);
    float e2 = fminf(fmaxf(__expf(l2), -10.f), 10.f);
    float inv = 1.f / (e1 + e2);
    float s1 = e1 * inv * n1;
    float s2 = e2 * inv * n2;

    unsigned short ob[24];
    #pragma unroll
    for (int c = 0; c < 6; ++c) {
        ob[c*4+0] = (unsigned short)f2bf(s1 * v1[c].x + s2 * v2[c].x);
        ob[c*4+1] = (unsigned short)f2bf(s1 * v1[c].y + s2 * v2[c].y);
        ob[c*4+2] = (unsigned short)f2bf(s1 * v1[c].z + s2 * v2[c].z);
        ob[c*4+3] = (unsigned short)f2bf(s1 * v1[c].w + s2 * v2[c].w);
    }
    uint4* op = reinterpret_cast<uint4*>(combb + (size_t)n * HIDF + q * 24);
    const uint4* ip = reinterpret_cast<const uint4*>(ob);
    op[0] = ip[0]; op[1] = ip[1]; op[2] = ip[2];
}

// ---------- GEMM2 (R4-proven): out = comb_bf16 @ W_fc.T + b_fc ----------
__global__ __launch_bounds__(256) void gemm_fc(
    const unsigned short* __restrict__ combb, const short* __restrict__ Bp2,
    const float* __restrict__ b_fc, float* __restrict__ out, int N)
{
    __shared__ short Bs[3 * 6 * 64 * 8];   // 18 KiB
    {
        const uint4* gsrc = reinterpret_cast<const uint4*>(Bp2);
        uint4* ldst = reinterpret_cast<uint4*>(Bs);
        for (int i = threadIdx.x; i < 3 * 6 * 64 * 8 / 8; i += 256) ldst[i] = gsrc[i];
    }
    __syncthreads();

    int lane = threadIdx.x & 63;
    int wid = threadIdx.x >> 6;
    int m0 = blockIdx.x * 64 + wid * 16;
    int arow = m0 + (lane & 15);
    int rc = arow < N ? arow : N - 1;
    const unsigned short* crow = combb + (size_t)rc * HIDF;
    int koff = (lane >> 4) << 3;

    f32x4 acc[6];
    #pragma unroll
    for (int nt = 0; nt < 6; ++nt) acc[nt] = (f32x4){0.f, 0.f, 0.f, 0.f};

    #pragma unroll
    for (int kt = 0; kt < 3; ++kt) {
        bf16x8 a8 = *reinterpret_cast<const bf16x8*>(crow + kt * 32 + koff);
        #pragma unroll
        for (int nt = 0; nt < 6; ++nt) {
            bf16x8 b8 = *reinterpret_cast<const bf16x8*>(&Bs[((kt * 6 + nt) * 64 + lane) * 8]);
            acc[nt] = __builtin_amdgcn_mfma_f32_16x16x32_bf16(a8, b8, acc[nt], 0, 0, 0);
        }
    }

    int rbase = m0 + ((lane >> 4) << 2);
    #pragma unroll
    for (int nt = 0; nt < 6; ++nt) {
        int col = nt * 16 + (lane & 15);
        float bf = b_fc[col];
        #pragma unroll
        for (int r = 0; r < 4; ++r) {
            int rrow = rbase + r;
            if (rrow < N) out[(size_t)rrow * HIDF + col] = acc[nt][r] + bf;
        }
    }
}

extern "C" void kernel_launch(void* const* d_in, const int* in_sizes, int n_in,
                              void* d_out, int out_size, void* d_ws, size_t ws_size,
                              hipStream_t stream) {
    const float* h     = (const float*)d_in[0];
    const float* norm1 = (const float*)d_in[1];
    const float* norm2 = (const float*)d_in[2];
    const int*   src1  = (const int*)d_in[3];
    const int*   dst1  = (const int*)d_in[4];
    const int*   src2  = (const int*)d_in[5];
    const int*   dst2  = (const int*)d_in[6];
    const float* W_lin = (const float*)d_in[7];
    const float* b_lin = (const float*)d_in[8];
    const float* W_fc  = (const float*)d_in[9];
    const float* b_fc  = (const float*)d_in[10];
    const float* W_al  = (const float*)d_in[11];
    const float* b_al  = (const float*)d_in[12];
    const float* W_ar  = (const float*)d_in[13];
    const float* b_ar  = (const float*)d_in[14];

    const int N = in_sizes[1];
    const int E = in_sizes[3];

    char* p = (char*)d_ws;
    auto alloc = [&](size_t bytes) {
        char* r = p;
        p += (bytes + 255) & ~(size_t)255;
        return r;
    };
    short* Bp1  = (short*)alloc((size_t)8 * 6 * 64 * 8 * 2);
    short* Bp2  = (short*)alloc((size_t)3 * 6 * 64 * 8 * 2);
    float* ai   = (float*)alloc((size_t)N * 4);
    unsigned short* linb  = (unsigned short*)alloc((size_t)N * HIDF * 2);
    unsigned short* combb = (unsigned short*)alloc((size_t)N * HIDF * 2);
    float* acc1 = (float*)alloc((size_t)N * HIDF * 4);
    float* acc2 = (float*)alloc((size_t)N * HIDF * 4);
    int*   cntp = (int*)alloc((size_t)2 * N * CNT_STRIDE * 4);
    int*   offs = (int*)alloc((size_t)2 * N * 4);
    int*   rank = (int*)alloc((size_t)2 * E * 4);
    int*   payload = (int*)alloc((size_t)2 * E * 4);
    int*   bsum = (int*)alloc(1024 * 4);

    const int n2N = 2 * N;
    const int nb  = (n2N + 255) / 256;

    hipMemsetAsync(cntp, 0, (size_t)n2N * CNT_STRIDE * 4, stream);

    int rankBlocks = (2 * E + 1023) / 1024;
    prep_rank<<<rankBlocks + 2, 256, 0, stream>>>(
        W_lin, W_fc, Bp1, Bp2, dst1, dst2, cntp, rank, E, N);

    scan_part<<<nb, 256, 0, stream>>>(cntp, offs, bsum, n2N);
    scan_top<<<1, 512, 0, stream>>>(bsum, nb);
    scan_add<<<nb, 256, 0, stream>>>(offs, bsum, n2N);
    place_kernel<<<(2 * E + 255) / 256, 256, 0, stream>>>(
        src1, dst1, src2, dst2, offs, rank, payload, E, N);

    int mblocks = (N + 63) / 64;
    gemm_lin<<<mblocks, 256, 0, stream>>>(h, Bp1, b_lin, W_al, b_al, linb, ai, N);

    int aggThreads = n2N * 12;
    agg_csr<<<(aggThreads + 255) / 256, 256, 0, stream>>>(
        linb, norm1, norm2, offs, payload, acc1, acc2, N, 2 * E);

    comb_c1<<<(4 * N + 255) / 256, 256, 0, stream>>>(
        acc1, acc2, norm1, norm2, ai, W_ar, b_ar, combb, N);

    gemm_fc<<<mblocks, 256, 0, stream>>>(combb, Bp2, b_fc, (float*)d_out, N);
}